// Round 7
// baseline (181.798 us; speedup 1.0000x reference)
//
#include <hip/hip_runtime.h>

// MACE symmetric contraction, B=4096 nodes, C=256 channels, I=16.
//
// Per (b,c):  s[b,c] = sum_p x_p * t[b,p],
//   t[b,p] = sum_{k<256} U3w[c,p,q,i]*x_q*x_i   (k=q*16+i)
//          + sum_q c2[c,p,q]*x_q (k=256+q)  +  c1[c,p] (k=272)
// => K=273 (pad 288=9*32) matmul on mfma_f32_16x16x32_bf16.
//
// R7: operand swap — A=coeff[p,k] (static per wave), B=y[k,node] built per
// tile. D[row=p, col=node]: p-reduction = 3 in-reg adds + 2 shuffle rounds
// (was 16 bpermutes over 4 rounds), epilogue x-read = 1 ds_read_b128 (was 4
// scalar), store = 16 contiguous dwords/wave. 2-way tile ILP for latency
// hiding. coeff fragment layout is IDENTICAL for A as B (lane&15 = M for A,
// N for B) so precompute is unchanged.
// NOTE: ~110 us of total dur_us is fixed harness overhead (constant R1-R6).

#define B_NODES 4096
#define C_CH    256
#define K3      23
#define K2      4

#define KSTEPS   9
#define KB_ELEMS (KSTEPS * 64 * 8)   // 4608 bf16 per channel
#define KB_U32   (KB_ELEMS / 2)      // 2304 u32 per channel

#define NODES_PER_BLK 128
#define SXS 68   // sx row stride in floats (64 data + 4 pad): 2-way-max banks

typedef short  short8 __attribute__((ext_vector_type(8)));
typedef float  f32x4  __attribute__((ext_vector_type(4)));

// ws layout (bytes): [bfrag: C*4608*2][sT: C*B*4]
static constexpr size_t OFF_BF_BYTES = 0;
static constexpr size_t OFF_ST_BYTES = (size_t)C_CH * KB_ELEMS * 2;

__device__ inline unsigned short f2bf_rne(float f) {
  union { float f; unsigned u; } v; v.f = f;
  unsigned r = v.u + 0x7FFFu + ((v.u >> 16) & 1u);
  return (unsigned short)(r >> 16);
}
__device__ inline unsigned fbits(float f) {
  union { float f; unsigned u; } v; v.f = f; return v.u;
}

// ---------------------------------------------------------------------------
// Kernel 1: coeff in fragment order (lane&15 = p, k = s*32+(lane>>4)*8+j).
// grid (9 steps, 32 channel-groups of 8); steps 0..7 stage a 47 KB U3 slice.
// ---------------------------------------------------------------------------
__global__ __launch_bounds__(256) void precompute_bfrag(
    const float* __restrict__ U3, const float* __restrict__ U2,
    const float* __restrict__ U1, const float* __restrict__ w3,
    const float* __restrict__ w2, const float* __restrict__ w1,
    unsigned int* __restrict__ bfrag_u32) {
  const int s  = blockIdx.x;        // K-step 0..8
  const int c0 = blockIdx.y * 8;    // 8 channels per block
  const int t  = threadIdx.x;
  const int lane = t >> 2;          // fragment lane
  const int jj   = (t & 3) * 2;     // 0,2,4,6
  const int p = lane & 15, g = lane >> 4;

  __shared__ float su3[512 * 23];   // rows: p*32 + qb*16 + i

  if (s < 8) {
    for (int l = t; l < 512 * 23; l += 256) {
      const int row = l / 23, col = l - row * 23;
      const int pp = row >> 5, qb = (row >> 4) & 1, ii = row & 15;
      su3[l] = U3[(size_t)((pp * 16 + (2 * s + qb)) * 16 + ii) * K3 + col];
    }
    __syncthreads();

    const int r0 = p * 32 + (g >> 1) * 16 + (g & 1) * 8 + jj;
    float u0[K3], u1[K3];
#pragma unroll
    for (int k3 = 0; k3 < K3; ++k3) {
      u0[k3] = su3[(size_t)r0 * K3 + k3];
      u1[k3] = su3[(size_t)(r0 + 1) * K3 + k3];
    }
#pragma unroll
    for (int ch = 0; ch < 8; ++ch) {
      const int c = c0 + ch;
      float a0 = 0.f, a1 = 0.f;
#pragma unroll
      for (int k3 = 0; k3 < K3; ++k3) {
        const float wv = w3[c * K3 + k3];   // uniform -> scalar load
        a0 += u0[k3] * wv;
        a1 += u1[k3] * wv;
      }
      bfrag_u32[(size_t)c * KB_U32 + s * 256 + t] =
          (unsigned)f2bf_rne(a0) | ((unsigned)f2bf_rne(a1) << 16);
    }
  } else {
    // s == 8: linear rows (x_q), constant row (k==272), pad 0.
#pragma unroll
    for (int ch = 0; ch < 8; ++ch) {
      const int c = c0 + ch;
      float v[2] = {0.f, 0.f};
#pragma unroll
      for (int e = 0; e < 2; ++e) {
        const int k = 256 + g * 8 + jj + e;
        if (k < 272) {
          const int q = k - 256;
          float a = 0.f;
#pragma unroll
          for (int k2 = 0; k2 < K2; ++k2)
            a += U2[(size_t)(p * 16 + q) * K2 + k2] * w2[c * K2 + k2];
          v[e] = a;
        } else if (k == 272) {
          v[e] = U1[p] * w1[c];
        }
      }
      bfrag_u32[(size_t)c * KB_U32 + s * 256 + t] =
          (unsigned)f2bf_rne(v[0]) | ((unsigned)f2bf_rne(v[1]) << 16);
    }
  }
}

// ---------------------------------------------------------------------------
// Kernel 2: MFMA contraction. Block = 256 thr (4 waves); wave w owns channel
// c0+w; block covers 128 nodes. x staged as 256B-contiguous chunks.
// A = coeff (regs), B = y monomials (built per tile), D[p, node].
// ---------------------------------------------------------------------------
__global__ __launch_bounds__(256)
__attribute__((amdgpu_waves_per_eu(2, 4)))
void contract_mfma(
    const float* __restrict__ x, const short8* __restrict__ bfragv,
    float* __restrict__ sT) {
  const int c0  = blockIdx.x * 4;              // channel group (fastest)
  const int nb0 = blockIdx.y * NODES_PER_BLK;
  const int t   = threadIdx.x;
  const int w = t >> 6, lane = t & 63, n = lane & 15, g = lane >> 4;

  __shared__ float sx[NODES_PER_BLK * SXS];    // [node][4ch x 16 + pad]

  // Coeff fragments for this wave's channel: 9 coalesced dwordx4 -> 36 VGPRs.
  short8 bf[KSTEPS];
  {
    const short8* bp = bfragv + (size_t)(c0 + w) * (KSTEPS * 64);
#pragma unroll
    for (int s = 0; s < KSTEPS; ++s) bf[s] = bp[s * 64 + lane];
  }

  // Stage x: 128 nodes * 16 chunks(16B) = 2048 chunks / 256 thr = 8 rounds.
#pragma unroll
  for (int r = 0; r < 8; ++r) {
    const int u = r * 256 + t;
    const int j = u >> 4, sub = u & 15;
    const float4 v = *(const float4*)(
        x + (size_t)(nb0 + j) * (C_CH * 16) + c0 * 16 + sub * 4);
    *(float4*)(sx + j * SXS + sub * 4) = v;
  }
  __syncthreads();

  const bool ghi = (g & 1) != 0;        // i-half: i = (g&1)*8 + j
  const bool gq  = ((g >> 1) & 1) != 0; // q = 2s + (g>>1)
  float* sTrow = sT + (size_t)(c0 + w) * B_NODES + nb0;

  for (int TT = 0; TT < 4; ++TT) {      // tile pairs: 2 independent chains
    const int T0 = TT * 2, T1 = TT * 2 + 1;

    // Derive per-lane x values for both tiles (lane's node = T*16 + n).
    float xh0[8], xq0[8], xh1[8], xq1[8];
#pragma unroll
    for (int half = 0; half < 2; ++half) {
      const int T = half ? T1 : T0;
      const float* xrow = sx + (size_t)(T * 16 + n) * SXS + w * 16;
      float xr[16];
#pragma unroll
      for (int v4 = 0; v4 < 4; ++v4) {
        float4 vv = *(const float4*)(xrow + v4 * 4);
        xr[v4 * 4 + 0] = vv.x; xr[v4 * 4 + 1] = vv.y;
        xr[v4 * 4 + 2] = vv.z; xr[v4 * 4 + 3] = vv.w;
      }
      float* xh = half ? xh1 : xh0;
      float* xq = half ? xq1 : xq0;
#pragma unroll
      for (int j = 0; j < 8; ++j) xh[j] = ghi ? xr[8 + j] : xr[j];
#pragma unroll
      for (int s = 0; s < 8; ++s) xq[s] = gq ? xr[2 * s + 1] : xr[2 * s];
    }

    f32x4 acc0 = (f32x4){0.f, 0.f, 0.f, 0.f};
    f32x4 acc1 = (f32x4){0.f, 0.f, 0.f, 0.f};

    // Steps 0..7: quadratic rows y[k] = x_q * x_i; two independent chains.
#pragma unroll
    for (int s = 0; s < 8; ++s) {
      union { unsigned u[4]; short8 v; } af0, af1;
#pragma unroll
      for (int m2 = 0; m2 < 4; ++m2) {
        const float a0 = xq0[s] * xh0[m2 * 2];
        const float a1 = xq0[s] * xh0[m2 * 2 + 1];
        af0.u[m2] = __builtin_amdgcn_perm(fbits(a1), fbits(a0), 0x07060302u);
        const float b0 = xq1[s] * xh1[m2 * 2];
        const float b1 = xq1[s] * xh1[m2 * 2 + 1];
        af1.u[m2] = __builtin_amdgcn_perm(fbits(b1), fbits(b0), 0x07060302u);
      }
      acc0 = __builtin_amdgcn_mfma_f32_16x16x32_bf16(bf[s], af0.v, acc0, 0, 0, 0);
      acc1 = __builtin_amdgcn_mfma_f32_16x16x32_bf16(bf[s], af1.v, acc1, 0, 0, 0);
    }
    // Step 8: linear rows (g<2 -> x half, matches ghi), const-1 (g==2,j==0).
    {
      union { unsigned u[4]; short8 v; } af0, af1;
#pragma unroll
      for (int m2 = 0; m2 < 4; ++m2) {
        float y00 = (g < 2) ? xh0[m2 * 2]     : 0.f;
        float y01 = (g < 2) ? xh0[m2 * 2 + 1] : 0.f;
        float y10 = (g < 2) ? xh1[m2 * 2]     : 0.f;
        float y11 = (g < 2) ? xh1[m2 * 2 + 1] : 0.f;
        if (m2 == 0) {
          y00 = (g == 2) ? 1.0f : y00;
          y10 = (g == 2) ? 1.0f : y10;
        }
        af0.u[m2] = __builtin_amdgcn_perm(fbits(y01), fbits(y00), 0x07060302u);
        af1.u[m2] = __builtin_amdgcn_perm(fbits(y11), fbits(y10), 0x07060302u);
      }
      acc0 = __builtin_amdgcn_mfma_f32_16x16x32_bf16(bf[8], af0.v, acc0, 0, 0, 0);
      acc1 = __builtin_amdgcn_mfma_f32_16x16x32_bf16(bf[8], af1.v, acc1, 0, 0, 0);
    }

    // Epilogue. D[row p = g*4+r][col node = n]:
    //   s[node] = sum_p t[p,node] * x[node][p]
    // lane reads x[n][g*4..g*4+3] (one b128), in-reg dot, butterfly over g.
    const float4 xv0 = *(const float4*)(sx + (size_t)(T0 * 16 + n) * SXS + w * 16 + g * 4);
    const float4 xv1 = *(const float4*)(sx + (size_t)(T1 * 16 + n) * SXS + w * 16 + g * 4);
    float v0 = acc0[0] * xv0.x + acc0[1] * xv0.y + acc0[2] * xv0.z + acc0[3] * xv0.w;
    float v1 = acc1[0] * xv1.x + acc1[1] * xv1.y + acc1[2] * xv1.z + acc1[3] * xv1.w;
    v0 += __shfl_xor(v0, 16); v1 += __shfl_xor(v1, 16);
    v0 += __shfl_xor(v0, 32); v1 += __shfl_xor(v1, 32);
    if (g == 0) {
      sTrow[T0 * 16 + n] = v0;
      sTrow[T1 * 16 + n] = v1;
    }
  }
}

// ---------------------------------------------------------------------------
// Kernel 3: out[b,d] = (1/16) * sum_c sT[c,b] * W[c,d]  (fp32, 64x64 tiles)
// ---------------------------------------------------------------------------
__global__ __launch_bounds__(256) void linear_kernel(
    const float* __restrict__ sT, const float* __restrict__ W,
    float* __restrict__ out) {
  const int b0 = blockIdx.x * 64;
  const int d0 = blockIdx.y * 64;
  const int t  = threadIdx.x;
  const int tx = t & 15;
  const int ty = t >> 4;

  __shared__ float As[16][64];
  __shared__ float Bs[16][64];
  float acc[4][4] = {};

  for (int k0 = 0; k0 < C_CH; k0 += 16) {
    const int kk  = t >> 6;
    const int col = t & 63;
#pragma unroll
    for (int r = 0; r < 4; ++r) {
      As[kk + r * 4][col] = sT[(size_t)(k0 + kk + r * 4) * B_NODES + b0 + col];
      Bs[kk + r * 4][col] = W[(size_t)(k0 + kk + r * 4) * C_CH + d0 + col];
    }
    __syncthreads();
#pragma unroll
    for (int k = 0; k < 16; ++k) {
      float a[4], bv[4];
#pragma unroll
      for (int i = 0; i < 4; ++i) a[i] = As[k][ty * 4 + i];
#pragma unroll
      for (int j = 0; j < 4; ++j) bv[j] = Bs[k][tx * 4 + j];
#pragma unroll
      for (int i = 0; i < 4; ++i)
#pragma unroll
        for (int j = 0; j < 4; ++j) acc[i][j] += a[i] * bv[j];
    }
    __syncthreads();
  }

#pragma unroll
  for (int i = 0; i < 4; ++i) {
    float4 v = make_float4(acc[i][0] * 0.0625f, acc[i][1] * 0.0625f,
                           acc[i][2] * 0.0625f, acc[i][3] * 0.0625f);
    *(float4*)(out + (size_t)(b0 + ty * 4 + i) * C_CH + d0 + tx * 4) = v;
  }
}

extern "C" void kernel_launch(void* const* d_in, const int* in_sizes, int n_in,
                              void* d_out, int out_size, void* d_ws, size_t ws_size,
                              hipStream_t stream) {
  const float* x  = (const float*)d_in[0];
  const float* U3 = (const float*)d_in[1];
  const float* U2 = (const float*)d_in[2];
  const float* U1 = (const float*)d_in[3];
  const float* w3 = (const float*)d_in[4];
  const float* w2 = (const float*)d_in[5];
  const float* w1 = (const float*)d_in[6];
  const float* Wl = (const float*)d_in[7];

  unsigned int* bfrag = (unsigned int*)((char*)d_ws + OFF_BF_BYTES);
  float*        sT    = (float*)((char*)d_ws + OFF_ST_BYTES);
  float*        out   = (float*)d_out;

  precompute_bfrag<<<dim3(KSTEPS, C_CH / 8), dim3(256), 0, stream>>>(
      U3, U2, U1, w3, w2, w1, bfrag);
  contract_mfma<<<dim3(C_CH / 4, B_NODES / NODES_PER_BLK), dim3(256), 0, stream>>>(
      x, (const short8*)bfrag, sT);
  linear_kernel<<<dim3(B_NODES / 64, C_CH / 64), dim3(256), 0, stream>>>(sT, Wl, out);
}